// Round 1
// 2428.026 us; speedup vs baseline: 1.1112x; 1.1112x over previous
//
#include <hip/hip_runtime.h>

// ---------------- constants ----------------
#define NV_V 50000
#define NV_D 300
#define NV_M 100
#define NV_H 8
#define NV_S 2048
#define NV_W 64
#define NV_D2 200
#define NV_B 2049   // S+1 sentences

typedef short bf16x8 __attribute__((ext_vector_type(8)));
typedef float f32x4 __attribute__((ext_vector_type(4)));

__device__ __forceinline__ float bf2f(unsigned short h) {
    return __uint_as_float(((unsigned int)h) << 16);
}
__device__ __forceinline__ unsigned short f2bf(float f) {
    unsigned int u = __float_as_uint(f);
    u += 0x7fffu + ((u >> 16) & 1u);
    return (unsigned short)(u >> 16);
}
__device__ __forceinline__ float sigm(float x) { return 1.0f / (1.0f + __expf(-x)); }
__device__ __forceinline__ float tanha(float x) { return 1.0f - 2.0f / (__expf(2.0f * x) + 1.0f); }

// ---------------- generic bf16 MFMA GEMM ----------------
// C[m][n] = sum_k A[m][k] * (transB ? Bt[n][k] : B[k][n])  (+ bias[n]) (rows >= *nvp zeroed)
#define BM 128
#define BN 64
#define BKK 32

__global__ __launch_bounds__(256) void gemm_bf16(
    const unsigned short* __restrict__ A, long lda, long sA,
    const unsigned short* __restrict__ B, long ldb, long sB, int transB,
    void* __restrict__ Cp, long ldc, long sC, int cbf16,
    const float* __restrict__ bias, const int* __restrict__ nvp,
    int M, int N, int K)
{
    __shared__ __align__(16) unsigned short As[BM][BKK + 8];
    __shared__ __align__(16) unsigned short Bs[BN][BKK + 8];
    int tid = threadIdx.x;
    int wave = tid >> 6, lane = tid & 63;
    int q = lane >> 4, l16 = lane & 15;
    long m0 = (long)blockIdx.x * BM;
    long n0 = (long)blockIdx.y * BN;
    long bz = blockIdx.z;
    A += bz * sA;
    B += bz * sB;

    f32x4 acc[2][4];
#pragma unroll
    for (int i = 0; i < 2; i++)
#pragma unroll
        for (int j = 0; j < 4; j++) acc[i][j] = (f32x4){0.f, 0.f, 0.f, 0.f};

    int nkk = (K + BKK - 1) / BKK;
    for (int kk = 0; kk < nkk; kk++) {
        int k0 = kk * BKK;
        {
            int row = tid >> 1;
            int kb = (tid & 1) * 16;
            long m = m0 + row;
            const unsigned short* src = A + m * lda + k0 + kb;
            if (m < M && (k0 + kb + 15) < K) {
#pragma unroll
                for (int j = 0; j < 4; j++)
                    *(uint2*)&As[row][kb + j * 4] = *(const uint2*)(src + j * 4);
            } else {
#pragma unroll
                for (int j = 0; j < 16; j++) {
                    int k = k0 + kb + j;
                    As[row][kb + j] = (m < M && k < K) ? src[j] : (unsigned short)0;
                }
            }
        }
        if (transB) {
            if (tid < 128) {
                int row = tid >> 1;
                int kb = (tid & 1) * 16;
                long n = n0 + row;
                const unsigned short* src = B + n * ldb + k0 + kb;
                if (n < N && (k0 + kb + 15) < K) {
#pragma unroll
                    for (int j = 0; j < 4; j++)
                        *(uint2*)&Bs[row][kb + j * 4] = *(const uint2*)(src + j * 4);
                } else {
#pragma unroll
                    for (int j = 0; j < 16; j++) {
                        int k = k0 + kb + j;
                        Bs[row][kb + j] = (n < N && k < K) ? src[j] : (unsigned short)0;
                    }
                }
            }
        } else {
            int krow = tid >> 3;
            int nb = (tid & 7) * 8;
            long k = k0 + krow;
            long n = n0 + nb;
            const unsigned short* src = B + k * ldb + n;
            unsigned short tmp[8];
            if (k < K && (n + 7) < N) {
                *(uint2*)&tmp[0] = *(const uint2*)(src);
                *(uint2*)&tmp[4] = *(const uint2*)(src + 4);
            } else {
#pragma unroll
                for (int j = 0; j < 8; j++) tmp[j] = (k < K && (n + j) < N) ? src[j] : (unsigned short)0;
            }
#pragma unroll
            for (int j = 0; j < 8; j++) Bs[nb + j][krow] = tmp[j];
        }
        __syncthreads();
        int mrow0 = wave * 32 + l16;
        bf16x8 a0 = *(const bf16x8*)&As[mrow0][q * 8];
        bf16x8 a1 = *(const bf16x8*)&As[mrow0 + 16][q * 8];
#pragma unroll
        for (int jn = 0; jn < 4; jn++) {
            bf16x8 bv = *(const bf16x8*)&Bs[jn * 16 + l16][q * 8];
            acc[0][jn] = __builtin_amdgcn_mfma_f32_16x16x32_bf16(a0, bv, acc[0][jn], 0, 0, 0);
            acc[1][jn] = __builtin_amdgcn_mfma_f32_16x16x32_bf16(a1, bv, acc[1][jn], 0, 0, 0);
        }
        __syncthreads();
    }

    int nv = nvp ? *nvp : (1 << 30);
#pragma unroll
    for (int i = 0; i < 2; i++) {
        long mbase = m0 + wave * 32 + i * 16 + q * 4;
#pragma unroll
        for (int jn = 0; jn < 4; jn++) {
            long n = n0 + jn * 16 + l16;
            if (n < N) {
                float badd = bias ? bias[n] : 0.0f;
#pragma unroll
                for (int r = 0; r < 4; r++) {
                    long m = mbase + r;
                    if (m < M) {
                        float v = acc[i][jn][r] + badd;
                        if (m >= nv) v = 0.0f;
                        long offc = bz * sC + m * ldc + n;
                        if (cbf16) ((unsigned short*)Cp)[offc] = f2bf(v);
                        else ((float*)Cp)[offc] = v;
                    }
                }
            }
        }
    }
}

// ---------------- weight prep ----------------
__global__ void prep_emb(const float* __restrict__ emb, unsigned short* __restrict__ embbf) {
    unsigned total = 50000u * 304u;
    for (unsigned idx = blockIdx.x * 256u + threadIdx.x; idx < total; idx += gridDim.x * 256u) {
        unsigned r = idx / 304u, c = idx - r * 304u;
        embbf[idx] = f2bf(c < 300u ? emb[r * 300u + c] : 0.f);
    }
}

__global__ void prep_misc(
    const float* __restrict__ wihf, const float* __restrict__ wihb,
    const float* __restrict__ whhf, const float* __restrict__ whhb,
    const float* __restrict__ bihf, const float* __restrict__ bhhf,
    const float* __restrict__ bihb, const float* __restrict__ bhhb,
    const float* __restrict__ qw, const float* __restrict__ qb,
    const float* __restrict__ kw, const float* __restrict__ kb,
    const float* __restrict__ vw, const float* __restrict__ vb,
    const float* __restrict__ cw,
    unsigned short* __restrict__ wih, unsigned short* __restrict__ whh, float* __restrict__ biasc,
    unsigned short* __restrict__ qkvw, float* __restrict__ qkvb, unsigned short* __restrict__ cwbf)
{
    const unsigned T1 = 800u * 304, T2 = 800u * 136, T3 = 800, T4 = 4800u * 200, T5 = 4800, T6 = 200u * 1600;
    unsigned total = T1 + T2 + T3 + T4 + T5 + T6;
    for (unsigned idx = blockIdx.x * 256u + threadIdx.x; idx < total; idx += gridDim.x * 256u) {
        unsigned t = idx;
        if (t < T1) {
            unsigned g = t / 304u, c = t - g * 304u;
            float v = 0.f;
            if (c < 300u) v = (g < 400u) ? wihf[g * 300u + c] : wihb[(g - 400u) * 300u + c];
            wih[t] = f2bf(v);
        } else if ((t -= T1) < T2) {
            unsigned g = t / 136u, c = t - g * 136u;
            float v = 0.f;
            if (c < 100u) v = (g < 400u) ? whhf[g * 100u + c] : whhb[(g - 400u) * 100u + c];
            whh[t] = f2bf(v);
        } else if ((t -= T2) < T3) {
            biasc[t] = (t < 400u) ? (bihf[t] + bhhf[t]) : (bihb[t - 400u] + bhhb[t - 400u]);
        } else if ((t -= T3) < T4) {
            unsigned n = t / 200u, i = t - n * 200u;
            unsigned sec = n / 1600u;
            unsigned ho = n - sec * 1600u;
            const float* w = sec == 0 ? qw : (sec == 1 ? kw : vw);
            qkvw[t] = f2bf(w[ho * 200u + i]);
        } else if ((t -= T4) < T5) {
            unsigned sec = t / 1600u, ho = t - sec * 1600u;
            const float* b = sec == 0 ? qb : (sec == 1 ? kb : vb);
            qkvb[t] = b[ho];
        } else {
            t -= T5;
            cwbf[t] = f2bf(cw[t]);
        }
    }
}

// ---------------- bidirectional LSTM recurrence (v3) ----------------
// v3 changes vs v2:
//  * NSENT 8->9: grid 514->456 blocks. At the ~256 unified-VGPR/wave this kernel
//    allocates (bfr weights = 112 VGPRs), only 2 blocks/CU are resident; 514 blocks
//    meant a serial second round of 2 blocks (661us = 2 x 330us). 456 <= 512 fits
//    in ONE residency round.
//  * input-projection gather: per-thread 16x scalar 2B loads -> block-cooperative
//    16B staged loads into a double-buffered LDS buffer (Xc). Loads are issued
//    right AFTER barrier-1 so their LLC/HBM latency hides under the pointwise/exp
//    phase and is drained at barrier-2 (every __syncthreads drains vmcnt(0)).
#define NSENT 9
#define NGRP 228   // ceil(2049/9)
__global__ __launch_bounds__(256, 2) void lstm_rec(
    const unsigned short* __restrict__ vp,   // [V][800] precomputed emb@W_ih^T (fwd|bwd)
    const unsigned short* __restrict__ whh,  // [800][136] (bf16, zero-padded K)
    const float* __restrict__ biasc,         // [800] b_ih+b_hh (fwd|bwd)
    const int* __restrict__ rsent, const int* __restrict__ body,
    float* __restrict__ hid)                 // [2049][200]
{
    __shared__ __align__(16) unsigned short Hl[16][152];    // h (bf16); rows 9..15 & cols>=100 stay 0
    __shared__ __align__(16) unsigned short Gl[NSENT][408]; // gate preacts (bf16)
    __shared__ __align__(16) unsigned short Xc[2][NSENT * 400]; // staged input projections (dir half)
    __shared__ int Tl[NSENT][64];                           // tokens
    int tid = threadIdx.x;
    int dir = blockIdx.x & 1;
    long s0 = (long)(blockIdx.x >> 1) * NSENT;
    int wave = tid >> 6, lane = tid & 63, q = lane >> 4, l16 = lane & 15;

    // load tokens
    for (int idx = tid; idx < NSENT * 64; idx += 256) {
        int sent = idx >> 6, t = idx & 63;
        long b = s0 + sent;
        int tok = 0;
        if (b == 0) tok = rsent[t];
        else if (b < NV_B) tok = body[(b - 1) * 64 + t];
        Tl[sent][t] = tok;
    }
    for (int idx = tid; idx < 16 * 152; idx += 256) ((unsigned short*)Hl)[idx] = 0;

    const unsigned short* whd = whh + (long)dir * 400 * 136;
    // A-operand fragments of w_hh: tile tt covers gates [tt*16, tt*16+16); lane holds
    // A[row=tt*16+l16][k=q*8+j]. 25 tiles split across 4 waves: tt = wave + 4*ii.
    bf16x8 bfr[7][4];
#pragma unroll
    for (int ii = 0; ii < 7; ii++) {
        int tt = wave + 4 * ii;
        if (tt < 25) {
#pragma unroll
            for (int kc = 0; kc < 4; kc++)
                bfr[ii][kc] = *(const bf16x8*)(whd + (long)(tt * 16 + l16) * 136 + kc * 32 + q * 8);
        }
    }
    // per-thread pointwise slots: p = tid + 256*i, i<4 (p<900)
    int psent[4], pm[4];
    float bc_r[4][4];
    float c_reg[4];
#pragma unroll
    for (int i = 0; i < 4; i++) {
        int p = tid + 256 * i;
        int sent = p / 100;
        int m = p - sent * 100;
        psent[i] = sent; pm[i] = m;
        c_reg[i] = 0.f;
        if (p < NSENT * 100) {
#pragma unroll
            for (int g = 0; g < 4; g++) bc_r[i][g] = biasc[dir * 400 + g * 100 + m];
        }
    }
    __syncthreads();

    const unsigned short* vpd = vp + dir * 400;
    // stage step 0's input projections into Xc[0] (visible at step-0's barrier-1)
    {
        int te0 = dir ? 63 : 0;
        for (int u = tid; u < NSENT * 50; u += 256) {
            int row = u / 50, c = u - row * 50;
            int tok = Tl[row][te0];
            *(bf16x8*)&Xc[0][u * 8] = *(const bf16x8*)(vpd + (long)tok * 800 + c * 8);
        }
    }

    for (int step = 0; step < 64; step++) {
        int buf = step & 1;
        // gates = w_hh @ h^T: C[gate][sent]
        f32x4 acc[7];
#pragma unroll
        for (int ii = 0; ii < 7; ii++) acc[ii] = (f32x4){0.f, 0.f, 0.f, 0.f};
#pragma unroll
        for (int kc = 0; kc < 4; kc++) {
            bf16x8 hv = *(const bf16x8*)&Hl[l16][kc * 32 + q * 8];
#pragma unroll
            for (int ii = 0; ii < 7; ii++) {
                int tt = wave + 4 * ii;
                if (tt < 25)
                    acc[ii] = __builtin_amdgcn_mfma_f32_16x16x32_bf16(bfr[ii][kc], hv, acc[ii], 0, 0, 0);
            }
        }
        // write: lane's 4 acc values are gates tt*16+q*4+r of sentence l16 -> one 8B store
        if (l16 < NSENT) {
#pragma unroll
            for (int ii = 0; ii < 7; ii++) {
                int tt = wave + 4 * ii;
                if (tt < 25) {
                    ushort4 us;
                    us.x = f2bf(acc[ii][0]); us.y = f2bf(acc[ii][1]);
                    us.z = f2bf(acc[ii][2]); us.w = f2bf(acc[ii][3]);
                    *(ushort4*)&Gl[l16][tt * 16 + q * 4] = us;
                }
            }
        }
        __syncthreads();   // barrier 1 (no vmem outstanding here -> cheap drain)

        // issue next step's staged loads NOW; latency hides under the pointwise
        // phase and is drained by barrier 2.
        bf16x8 stg0, stg1;
        int u1 = tid + 256;
        if (step < 63) {
            int te2 = dir ? (62 - step) : (step + 1);
            {
                int row = tid / 50, c = tid - row * 50;
                int tok = Tl[row][te2];
                stg0 = *(const bf16x8*)(vpd + (long)tok * 800 + c * 8);
            }
            if (u1 < NSENT * 50) {
                int row = u1 / 50, c = u1 - row * 50;
                int tok = Tl[row][te2];
                stg1 = *(const bf16x8*)(vpd + (long)tok * 800 + c * 8);
            }
        }

        // pointwise LSTM cell update
#pragma unroll
        for (int i = 0; i < 4; i++) {
            int p = tid + 256 * i;
            if (p < NSENT * 100) {
                int sent = psent[i], m = pm[i];
                const unsigned short* xr = &Xc[buf][sent * 400 + m];
                float gi = bf2f(Gl[sent][m])       + bf2f(xr[0])   + bc_r[i][0];
                float gf = bf2f(Gl[sent][100 + m]) + bf2f(xr[100]) + bc_r[i][1];
                float gg = bf2f(Gl[sent][200 + m]) + bf2f(xr[200]) + bc_r[i][2];
                float go = bf2f(Gl[sent][300 + m]) + bf2f(xr[300]) + bc_r[i][3];
                float c = sigm(gf) * c_reg[i] + sigm(gi) * tanha(gg);
                float h = sigm(go) * tanha(c);
                c_reg[i] = c;
                Hl[sent][m] = f2bf(h);
                if (step == 63) {
                    long b = s0 + sent;
                    if (b < NV_B) hid[b * 200 + dir * 100 + m] = h;
                }
            }
        }
        // land staged inputs into the other buffer (vmcnt waited here, post-pointwise)
        if (step < 63) {
            *(bf16x8*)&Xc[buf ^ 1][tid * 8] = stg0;
            if (u1 < NSENT * 50) *(bf16x8*)&Xc[buf ^ 1][u1 * 8] = stg1;
        }
        __syncthreads();   // barrier 2
    }
}

// ---------------- similarity / partition glue ----------------
__global__ void k_u(const float* __restrict__ hid, const float* __restrict__ simw, float* __restrict__ u) {
    int j = threadIdx.x;
    if (j < 200) {
        float s = 0.f;
        for (int a = 0; a < 200; a++) s += hid[a] * simw[a * 200 + j];
        u[j] = s;
    }
}

__global__ void k_logits(const float* __restrict__ hid, const float* __restrict__ u,
                         const float* __restrict__ simb, float* __restrict__ logits) {
    int s = blockIdx.x * 256 + threadIdx.x;
    if (s < NV_S) {
        const float* row = hid + (long)(1 + s) * 200;
        float acc = 0.f;
        for (int j = 0; j < 200; j++) acc += row[j] * u[j];
        logits[s] = acc + simb[0];
    }
}

__global__ __launch_bounds__(256) void k_glue(const float* __restrict__ logits, float* __restrict__ prob,
                                              int* __restrict__ dhigh, int* __restrict__ dlow,
                                              int* __restrict__ counts) {
    __shared__ float red[256];
    __shared__ int cnt[256];
    __shared__ float smax, ssum;
    __shared__ int offs[257];
    int tid = threadIdx.x;
    float sg[8];
    int mk[8];
    float lmax = -3e38f;
    int lc = 0;
#pragma unroll
    for (int i = 0; i < 8; i++) {
        int s = tid * 8 + i;
        float x = 1.f / (1.f + __expf(-logits[s]));
        sg[i] = x;
        mk[i] = (x >= 0.5f) ? 1 : 0;
        lc += mk[i];
        lmax = fmaxf(lmax, x);
    }
    red[tid] = lmax;
    cnt[tid] = lc;
    __syncthreads();
    for (int d = 128; d > 0; d >>= 1) {
        if (tid < d) red[tid] = fmaxf(red[tid], red[tid + d]);
        __syncthreads();
    }
    if (tid == 0) smax = red[0];
    __syncthreads();
    float le = 0.f;
#pragma unroll
    for (int i = 0; i < 8; i++) le += __expf(sg[i] - smax);
    red[tid] = le;
    __syncthreads();
    for (int d = 128; d > 0; d >>= 1) {
        if (tid < d) red[tid] += red[tid + d];
        __syncthreads();
    }
    if (tid == 0) {
        ssum = red[0];
        int run = 0;
        for (int i = 0; i < 256; i++) { offs[i] = run; run += cnt[i]; }
        offs[256] = run;
        counts[0] = run;
        counts[1] = NV_S - run;
    }
    __syncthreads();
    int nh = offs[256];
    int tpos = offs[tid];
    int fpos = tid * 8 - tpos;
    float inv = 1.f / ssum;
#pragma unroll
    for (int i = 0; i < 8; i++) {
        int s = tid * 8 + i;
        prob[s] = __expf(sg[i] - smax) * inv;
        if (mk[i]) { dhigh[s] = tpos; dlow[s] = (NV_S - nh) + tpos; tpos++; }
        else { dhigh[s] = nh + fpos; dlow[s] = fpos; fpos++; }
    }
}

__global__ void k_scatter(const float* __restrict__ hid, const float* __restrict__ prob,
                          const int* __restrict__ dhigh, const int* __restrict__ dlow,
                          unsigned short* __restrict__ Xh, unsigned short* __restrict__ Xl) {
    int s = blockIdx.x;
    int j = threadIdx.x;
    if (j < 200) {
        float v = prob[s] * hid[(long)(1 + s) * 200 + j];
        unsigned short b = f2bf(v);
        Xh[(long)dhigh[s] * 200 + j] = b;
        Xl[(long)dlow[s] * 200 + j] = b;
    }
}

// ---------------- column softmax (over s, per (h,t)), rewrites S->P in place ----------------
__global__ __launch_bounds__(256) void k_colsoft(unsigned short* __restrict__ Sb,
                                                 const int* __restrict__ nvp, int indicator) {
    __shared__ float redm[4][64];
    __shared__ float cm[64], zz[64];
    int tid = threadIdx.x;
    int tx = tid & 63, ty = tid >> 6;
    int h = blockIdx.y;
    int t = blockIdx.x * 64 + tx;
    int nv = *nvp;
    unsigned short* Sh = Sb + (long)h * NV_S * NV_S;
    const float inv = 0.0707106781f;  // 1/sqrt(200)
    float pm = -3e38f;
    for (int s = ty; s < NV_S; s += 4) {
        float v = bf2f(Sh[(long)s * NV_S + t]);
        float f = indicator ? v * inv : (1.f - v) * inv;
        if (s >= nv) f = -1e30f;
        pm = fmaxf(pm, f);
    }
    redm[ty][tx] = pm;
    __syncthreads();
    if (ty == 0) cm[tx] = fmaxf(fmaxf(redm[0][tx], redm[1][tx]), fmaxf(redm[2][tx], redm[3][tx]));
    __syncthreads();
    float cmv = cm[tx];
    float ps = 0.f;
    for (int s = ty; s < NV_S; s += 4) {
        float v = bf2f(Sh[(long)s * NV_S + t]);
        float f = indicator ? v * inv : (1.f - v) * inv;
        if (s >= nv) f = -1e30f;
        ps += __expf(f - cmv);
    }
    redm[ty][tx] = ps;
    __syncthreads();
    if (ty == 0) zz[tx] = redm[0][tx] + redm[1][tx] + redm[2][tx] + redm[3][tx];
    __syncthreads();
    float zi = 1.f / zz[tx];
    float tmask = (t < nv) ? 1.f : 0.f;
    for (int s = ty; s < NV_S; s += 4) {
        float v = bf2f(Sh[(long)s * NV_S + t]);
        float f = indicator ? v * inv : (1.f - v) * inv;
        float p = (s < nv) ? (__expf(f - cmv) * zi * tmask) : 0.f;
        Sh[(long)s * NV_S + t] = f2bf(p);
    }
}

// ---------------- final feature matvec ----------------
__global__ void k_initout(const float* __restrict__ featb, float* __restrict__ out) {
    int j = threadIdx.x + blockIdx.x * 256;
    if (j < 400) out[j] = featb[j % 200];
}

__global__ __launch_bounds__(256) void k_feat(const float* __restrict__ mh, const float* __restrict__ featw,
                                              float* __restrict__ out) {
    __shared__ float red0[256], red1[256];
    int j = blockIdx.x, ch = blockIdx.y, tid = threadIdx.x;
    long base = (long)ch * 102400;
    const float4* wrow = (const float4*)(featw + (long)j * 409600 + base);
    const float4* mh_h = (const float4*)(mh + base);
    const float4* mh_l = (const float4*)(mh + 409600 + base);
    float ah = 0.f, al = 0.f;
    for (int r = tid; r < 25600; r += 256) {
        float4 w = wrow[r];
        float4 a = mh_h[r];
        float4 b = mh_l[r];
        ah += w.x * a.x + w.y * a.y + w.z * a.z + w.w * a.w;
        al += w.x * b.x + w.y * b.y + w.z * b.z + w.w * b.w;
    }
    red0[tid] = ah;
    red1[tid] = al;
    __syncthreads();
    for (int d = 128; d > 0; d >>= 1) {
        if (tid < d) { red0[tid] += red0[tid + d]; red1[tid] += red1[tid + d]; }
        __syncthreads();
    }
    if (tid == 0) {
        atomicAdd(&out[j], red0[0]);
        atomicAdd(&out[200 + j], red1[0]);
    }
}

// ---------------- host launch ----------------
extern "C" void kernel_launch(void* const* d_in, const int* in_sizes, int n_in,
                              void* d_out, int out_size, void* d_ws, size_t ws_size,
                              hipStream_t stream) {
    const int* rsent = (const int*)d_in[0];
    const int* body = (const int*)d_in[1];
    const float* emb = (const float*)d_in[2];
    const float* wihf = (const float*)d_in[3];
    const float* whhf = (const float*)d_in[4];
    const float* bihf = (const float*)d_in[5];
    const float* bihf2 = (const float*)d_in[6];
    const float* wihb = (const float*)d_in[7];
    const float* whhb = (const float*)d_in[8];
    const float* bihb = (const float*)d_in[9];
    const float* bhhb = (const float*)d_in[10];
    const float* simw = (const float*)d_in[11];
    const float* simb = (const float*)d_in[12];
    const float* qw = (const float*)d_in[13];
    const float* qb = (const float*)d_in[14];
    const float* kw = (const float*)d_in[15];
    const float* kb = (const float*)d_in[16];
    const float* vw = (const float*)d_in[17];
    const float* vb = (const float*)d_in[18];
    const float* cw = (const float*)d_in[19];
    const float* cb = (const float*)d_in[20];
    const float* fw = (const float*)d_in[21];
    const float* fb = (const float*)d_in[22];
    const float* bhhf = bihf2;
    float* out = (float*)d_out;

    char* ws = (char*)d_ws;
    size_t off = 0;
    auto alloc = [&](size_t b) -> void* {
        void* p = ws + off;
        off += (b + 255) & ~(size_t)255;
        return p;
    };
    unsigned short* embbf = (unsigned short*)alloc(50000L * 304 * 2);
    unsigned short* wih = (unsigned short*)alloc(800L * 304 * 2);
    unsigned short* whh = (unsigned short*)alloc(800L * 136 * 2);
    float* biasc = (float*)alloc(800 * 4);
    unsigned short* qkvw = (unsigned short*)alloc(4800L * 200 * 2);
    float* qkvb = (float*)alloc(4800 * 4);
    unsigned short* cwbf = (unsigned short*)alloc(200L * 1600 * 2);
    unsigned short* vpb = (unsigned short*)alloc(50000L * 800 * 2);
    float* hid = (float*)alloc(2049L * 200 * 4);
    float* u = (float*)alloc(200 * 4);
    float* logits = (float*)alloc(2048 * 4);
    float* prob = (float*)alloc(2048 * 4);
    int* cnts = (int*)alloc(64);
    int* dh = (int*)alloc(2048 * 4);
    int* dl = (int*)alloc(2048 * 4);
    unsigned short* Xh = (unsigned short*)alloc(2048L * 200 * 2);
    unsigned short* Xl = (unsigned short*)alloc(2048L * 200 * 2);
    unsigned short* qkvbuf = (unsigned short*)alloc(2048L * 4800 * 2);
    unsigned short* sbuf = (unsigned short*)alloc(8L * 2048 * 2048 * 2);
    unsigned short* catb = (unsigned short*)alloc(2048L * 1600 * 2);
    float* mhbuf = (float*)alloc(2L * 409600 * 4);

    prep_emb<<<2048, 256, 0, stream>>>(emb, embbf);
    prep_misc<<<2048, 256, 0, stream>>>(wihf, wihb, whhf, whhb, bihf, bhhf, bihb, bhhb,
                                        qw, qb, kw, kb, vw, vb, cw,
                                        wih, whh, biasc, qkvw, qkvb, cwbf);
    // vocab-wide input projection: [V,300] @ [300,800]
    gemm_bf16<<<dim3(391, 13, 1), 256, 0, stream>>>(
        embbf, 304L, 0L, wih, 304L, 0L, 1,
        vpb, 800L, 0L, 1, nullptr, nullptr, 50000, 800, 300);
    lstm_rec<<<2 * NGRP, 256, 0, stream>>>(vpb, whh, biasc, rsent, body, hid);
    k_u<<<1, 256, 0, stream>>>(hid, simw, u);
    k_logits<<<8, 256, 0, stream>>>(hid, u, simb, logits);
    k_glue<<<1, 256, 0, stream>>>(logits, prob, dh, dl, cnts);
    k_scatter<<<2048, 256, 0, stream>>>(hid, prob, dh, dl, Xh, Xl);

    for (int br = 0; br < 2; br++) {
        const unsigned short* X = (br == 0) ? Xh : Xl;
        const int* nvp = cnts + br;
        // QKV projection: [2048,200] @ [200,4800] + bias
        gemm_bf16<<<dim3(16, 75, 1), 256, 0, stream>>>(
            X, 200L, 0L, qkvw, 200L, 0L, 1,
            qkvbuf, 4800L, 0L, 1, qkvb, nullptr, 2048, 4800, 200);
        // scores: per head Q_h @ K_h^T -> [8][2048][2048]
        gemm_bf16<<<dim3(16, 32, 8), 256, 0, stream>>>(
            qkvbuf, 4800L, 200L, qkvbuf + 1600, 4800L, 200L, 1,
            sbuf, 2048L, (long)2048 * 2048, 1, nullptr, nullptr, 2048, 2048, 200);
        // column softmax (over s), writes P in place
        k_colsoft<<<dim3(32, 8, 1), 256, 0, stream>>>(sbuf, nvp, br == 0 ? 1 : 0);
        // out = P @ V -> cat[s][h*200+o]
        gemm_bf16<<<dim3(16, 4, 8), 256, 0, stream>>>(
            sbuf, 2048L, (long)2048 * 2048, qkvbuf + 3200, 4800L, 200L, 0,
            catb, 1600L, 200L, 1, nullptr, nullptr, 2048, 200, 2048);
        // mh = cat @ concat_w^T + cb, rows >= n_valid zeroed
        gemm_bf16<<<dim3(16, 4, 1), 256, 0, stream>>>(
            catb, 1600L, 0L, cwbf, 1600L, 0L, 1,
            mhbuf + (long)br * 409600, 200L, 0L, 0, cb, nvp, 2048, 200, 1600);
    }
    k_initout<<<2, 256, 0, stream>>>(fb, out);
    k_feat<<<dim3(200, 4, 1), 256, 0, stream>>>(mhbuf, fw, out);
}

// Round 2
// 1646.606 us; speedup vs baseline: 1.6385x; 1.4746x over previous
//
#include <hip/hip_runtime.h>

// ---------------- constants ----------------
#define NV_V 50000
#define NV_D 300
#define NV_M 100
#define NV_H 8
#define NV_S 2048
#define NV_W 64
#define NV_D2 200
#define NV_B 2049   // S+1 sentences

typedef short bf16x8 __attribute__((ext_vector_type(8)));
typedef float f32x4 __attribute__((ext_vector_type(4)));

__device__ __forceinline__ float bf2f(unsigned short h) {
    return __uint_as_float(((unsigned int)h) << 16);
}
__device__ __forceinline__ unsigned short f2bf(float f) {
    unsigned int u = __float_as_uint(f);
    u += 0x7fffu + ((u >> 16) & 1u);
    return (unsigned short)(u >> 16);
}
__device__ __forceinline__ float sigm(float x) { return 1.0f / (1.0f + __expf(-x)); }
__device__ __forceinline__ float tanha(float x) { return 1.0f - 2.0f / (__expf(2.0f * x) + 1.0f); }

// ---------------- generic bf16 MFMA GEMM ----------------
// C[m][n] = sum_k A[m][k] * (transB ? Bt[n][k] : B[k][n])  (+ bias[n]) (rows >= *nvp zeroed)
#define BM 128
#define BN 64
#define BKK 32

__global__ __launch_bounds__(256) void gemm_bf16(
    const unsigned short* __restrict__ A, long lda, long sA,
    const unsigned short* __restrict__ B, long ldb, long sB, int transB,
    void* __restrict__ Cp, long ldc, long sC, int cbf16,
    const float* __restrict__ bias, const int* __restrict__ nvp,
    int M, int N, int K)
{
    __shared__ __align__(16) unsigned short As[BM][BKK + 8];
    __shared__ __align__(16) unsigned short Bs[BN][BKK + 8];
    int tid = threadIdx.x;
    int wave = tid >> 6, lane = tid & 63;
    int q = lane >> 4, l16 = lane & 15;
    long m0 = (long)blockIdx.x * BM;
    long n0 = (long)blockIdx.y * BN;
    long bz = blockIdx.z;
    A += bz * sA;
    B += bz * sB;

    f32x4 acc[2][4];
#pragma unroll
    for (int i = 0; i < 2; i++)
#pragma unroll
        for (int j = 0; j < 4; j++) acc[i][j] = (f32x4){0.f, 0.f, 0.f, 0.f};

    int nkk = (K + BKK - 1) / BKK;
    for (int kk = 0; kk < nkk; kk++) {
        int k0 = kk * BKK;
        {
            int row = tid >> 1;
            int kb = (tid & 1) * 16;
            long m = m0 + row;
            const unsigned short* src = A + m * lda + k0 + kb;
            if (m < M && (k0 + kb + 15) < K) {
#pragma unroll
                for (int j = 0; j < 4; j++)
                    *(uint2*)&As[row][kb + j * 4] = *(const uint2*)(src + j * 4);
            } else {
#pragma unroll
                for (int j = 0; j < 16; j++) {
                    int k = k0 + kb + j;
                    As[row][kb + j] = (m < M && k < K) ? src[j] : (unsigned short)0;
                }
            }
        }
        if (transB) {
            if (tid < 128) {
                int row = tid >> 1;
                int kb = (tid & 1) * 16;
                long n = n0 + row;
                const unsigned short* src = B + n * ldb + k0 + kb;
                if (n < N && (k0 + kb + 15) < K) {
#pragma unroll
                    for (int j = 0; j < 4; j++)
                        *(uint2*)&Bs[row][kb + j * 4] = *(const uint2*)(src + j * 4);
                } else {
#pragma unroll
                    for (int j = 0; j < 16; j++) {
                        int k = k0 + kb + j;
                        Bs[row][kb + j] = (n < N && k < K) ? src[j] : (unsigned short)0;
                    }
                }
            }
        } else {
            int krow = tid >> 3;
            int nb = (tid & 7) * 8;
            long k = k0 + krow;
            long n = n0 + nb;
            const unsigned short* src = B + k * ldb + n;
            unsigned short tmp[8];
            if (k < K && (n + 7) < N) {
                *(uint2*)&tmp[0] = *(const uint2*)(src);
                *(uint2*)&tmp[4] = *(const uint2*)(src + 4);
            } else {
#pragma unroll
                for (int j = 0; j < 8; j++) tmp[j] = (k < K && (n + j) < N) ? src[j] : (unsigned short)0;
            }
#pragma unroll
            for (int j = 0; j < 8; j++) Bs[nb + j][krow] = tmp[j];
        }
        __syncthreads();
        int mrow0 = wave * 32 + l16;
        bf16x8 a0 = *(const bf16x8*)&As[mrow0][q * 8];
        bf16x8 a1 = *(const bf16x8*)&As[mrow0 + 16][q * 8];
#pragma unroll
        for (int jn = 0; jn < 4; jn++) {
            bf16x8 bv = *(const bf16x8*)&Bs[jn * 16 + l16][q * 8];
            acc[0][jn] = __builtin_amdgcn_mfma_f32_16x16x32_bf16(a0, bv, acc[0][jn], 0, 0, 0);
            acc[1][jn] = __builtin_amdgcn_mfma_f32_16x16x32_bf16(a1, bv, acc[1][jn], 0, 0, 0);
        }
        __syncthreads();
    }

    int nv = nvp ? *nvp : (1 << 30);
#pragma unroll
    for (int i = 0; i < 2; i++) {
        long mbase = m0 + wave * 32 + i * 16 + q * 4;
#pragma unroll
        for (int jn = 0; jn < 4; jn++) {
            long n = n0 + jn * 16 + l16;
            if (n < N) {
                float badd = bias ? bias[n] : 0.0f;
#pragma unroll
                for (int r = 0; r < 4; r++) {
                    long m = mbase + r;
                    if (m < M) {
                        float v = acc[i][jn][r] + badd;
                        if (m >= nv) v = 0.0f;
                        long offc = bz * sC + m * ldc + n;
                        if (cbf16) ((unsigned short*)Cp)[offc] = f2bf(v);
                        else ((float*)Cp)[offc] = v;
                    }
                }
            }
        }
    }
}

// ---------------- weight prep ----------------
__global__ void prep_emb(const float* __restrict__ emb, unsigned short* __restrict__ embbf) {
    unsigned total = 50000u * 304u;
    for (unsigned idx = blockIdx.x * 256u + threadIdx.x; idx < total; idx += gridDim.x * 256u) {
        unsigned r = idx / 304u, c = idx - r * 304u;
        embbf[idx] = f2bf(c < 300u ? emb[r * 300u + c] : 0.f);
    }
}

__global__ void prep_misc(
    const float* __restrict__ wihf, const float* __restrict__ wihb,
    const float* __restrict__ whhf, const float* __restrict__ whhb,
    const float* __restrict__ bihf, const float* __restrict__ bhhf,
    const float* __restrict__ bihb, const float* __restrict__ bhhb,
    const float* __restrict__ qw, const float* __restrict__ qb,
    const float* __restrict__ kw, const float* __restrict__ kb,
    const float* __restrict__ vw, const float* __restrict__ vb,
    const float* __restrict__ cw,
    unsigned short* __restrict__ wih, unsigned short* __restrict__ whh, float* __restrict__ biasc,
    unsigned short* __restrict__ qkvw, float* __restrict__ qkvb, unsigned short* __restrict__ cwbf)
{
    const unsigned T1 = 800u * 304, T2 = 800u * 136, T3 = 800, T4 = 4800u * 200, T5 = 4800, T6 = 200u * 1600;
    unsigned total = T1 + T2 + T3 + T4 + T5 + T6;
    for (unsigned idx = blockIdx.x * 256u + threadIdx.x; idx < total; idx += gridDim.x * 256u) {
        unsigned t = idx;
        if (t < T1) {
            unsigned g = t / 304u, c = t - g * 304u;
            float v = 0.f;
            if (c < 300u) v = (g < 400u) ? wihf[g * 300u + c] : wihb[(g - 400u) * 300u + c];
            wih[t] = f2bf(v);
        } else if ((t -= T1) < T2) {
            unsigned g = t / 136u, c = t - g * 136u;
            float v = 0.f;
            if (c < 100u) v = (g < 400u) ? whhf[g * 100u + c] : whhb[(g - 400u) * 100u + c];
            whh[t] = f2bf(v);
        } else if ((t -= T2) < T3) {
            biasc[t] = (t < 400u) ? (bihf[t] + bhhf[t]) : (bihb[t - 400u] + bhhb[t - 400u]);
        } else if ((t -= T3) < T4) {
            unsigned n = t / 200u, i = t - n * 200u;
            unsigned sec = n / 1600u;
            unsigned ho = n - sec * 1600u;
            const float* w = sec == 0 ? qw : (sec == 1 ? kw : vw);
            qkvw[t] = f2bf(w[ho * 200u + i]);
        } else if ((t -= T4) < T5) {
            unsigned sec = t / 1600u, ho = t - sec * 1600u;
            const float* b = sec == 0 ? qb : (sec == 1 ? kb : vb);
            qkvb[t] = b[ho];
        } else {
            t -= T5;
            cwbf[t] = f2bf(cw[t]);
        }
    }
}

// ---------------- bidirectional LSTM recurrence (v3) ----------------
#define NSENT 9
#define NGRP 228   // ceil(2049/9)
__global__ __launch_bounds__(256, 2) void lstm_rec(
    const unsigned short* __restrict__ vp,   // [V][800] precomputed emb@W_ih^T (fwd|bwd)
    const unsigned short* __restrict__ whh,  // [800][136] (bf16, zero-padded K)
    const float* __restrict__ biasc,         // [800] b_ih+b_hh (fwd|bwd)
    const int* __restrict__ rsent, const int* __restrict__ body,
    float* __restrict__ hid)                 // [2049][200]
{
    __shared__ __align__(16) unsigned short Hl[16][152];    // h (bf16); rows 9..15 & cols>=100 stay 0
    __shared__ __align__(16) unsigned short Gl[NSENT][408]; // gate preacts (bf16)
    __shared__ __align__(16) unsigned short Xc[2][NSENT * 400]; // staged input projections (dir half)
    __shared__ int Tl[NSENT][64];                           // tokens
    int tid = threadIdx.x;
    int dir = blockIdx.x & 1;
    long s0 = (long)(blockIdx.x >> 1) * NSENT;
    int wave = tid >> 6, lane = tid & 63, q = lane >> 4, l16 = lane & 15;

    // load tokens
    for (int idx = tid; idx < NSENT * 64; idx += 256) {
        int sent = idx >> 6, t = idx & 63;
        long b = s0 + sent;
        int tok = 0;
        if (b == 0) tok = rsent[t];
        else if (b < NV_B) tok = body[(b - 1) * 64 + t];
        Tl[sent][t] = tok;
    }
    for (int idx = tid; idx < 16 * 152; idx += 256) ((unsigned short*)Hl)[idx] = 0;

    const unsigned short* whd = whh + (long)dir * 400 * 136;
    // A-operand fragments of w_hh: tile tt covers gates [tt*16, tt*16+16); lane holds
    // A[row=tt*16+l16][k=q*8+j]. 25 tiles split across 4 waves: tt = wave + 4*ii.
    bf16x8 bfr[7][4];
#pragma unroll
    for (int ii = 0; ii < 7; ii++) {
        int tt = wave + 4 * ii;
        if (tt < 25) {
#pragma unroll
            for (int kc = 0; kc < 4; kc++)
                bfr[ii][kc] = *(const bf16x8*)(whd + (long)(tt * 16 + l16) * 136 + kc * 32 + q * 8);
        }
    }
    // per-thread pointwise slots: p = tid + 256*i, i<4 (p<900)
    int psent[4], pm[4];
    float bc_r[4][4];
    float c_reg[4];
#pragma unroll
    for (int i = 0; i < 4; i++) {
        int p = tid + 256 * i;
        int sent = p / 100;
        int m = p - sent * 100;
        psent[i] = sent; pm[i] = m;
        c_reg[i] = 0.f;
        if (p < NSENT * 100) {
#pragma unroll
            for (int g = 0; g < 4; g++) bc_r[i][g] = biasc[dir * 400 + g * 100 + m];
        }
    }
    __syncthreads();

    const unsigned short* vpd = vp + dir * 400;
    // stage step 0's input projections into Xc[0]
    {
        int te0 = dir ? 63 : 0;
        for (int u = tid; u < NSENT * 50; u += 256) {
            int row = u / 50, c = u - row * 50;
            int tok = Tl[row][te0];
            *(bf16x8*)&Xc[0][u * 8] = *(const bf16x8*)(vpd + (long)tok * 800 + c * 8);
        }
    }

    for (int step = 0; step < 64; step++) {
        int buf = step & 1;
        // gates = w_hh @ h^T: C[gate][sent]
        f32x4 acc[7];
#pragma unroll
        for (int ii = 0; ii < 7; ii++) acc[ii] = (f32x4){0.f, 0.f, 0.f, 0.f};
#pragma unroll
        for (int kc = 0; kc < 4; kc++) {
            bf16x8 hv = *(const bf16x8*)&Hl[l16][kc * 32 + q * 8];
#pragma unroll
            for (int ii = 0; ii < 7; ii++) {
                int tt = wave + 4 * ii;
                if (tt < 25)
                    acc[ii] = __builtin_amdgcn_mfma_f32_16x16x32_bf16(bfr[ii][kc], hv, acc[ii], 0, 0, 0);
            }
        }
        // write: lane's 4 acc values are gates tt*16+q*4+r of sentence l16 -> one 8B store
        if (l16 < NSENT) {
#pragma unroll
            for (int ii = 0; ii < 7; ii++) {
                int tt = wave + 4 * ii;
                if (tt < 25) {
                    ushort4 us;
                    us.x = f2bf(acc[ii][0]); us.y = f2bf(acc[ii][1]);
                    us.z = f2bf(acc[ii][2]); us.w = f2bf(acc[ii][3]);
                    *(ushort4*)&Gl[l16][tt * 16 + q * 4] = us;
                }
            }
        }
        __syncthreads();   // barrier 1

        // issue next step's staged loads NOW; latency hides under the pointwise phase
        bf16x8 stg0, stg1;
        int u1 = tid + 256;
        if (step < 63) {
            int te2 = dir ? (62 - step) : (step + 1);
            {
                int row = tid / 50, c = tid - row * 50;
                int tok = Tl[row][te2];
                stg0 = *(const bf16x8*)(vpd + (long)tok * 800 + c * 8);
            }
            if (u1 < NSENT * 50) {
                int row = u1 / 50, c = u1 - row * 50;
                int tok = Tl[row][te2];
                stg1 = *(const bf16x8*)(vpd + (long)tok * 800 + c * 8);
            }
        }

        // pointwise LSTM cell update
#pragma unroll
        for (int i = 0; i < 4; i++) {
            int p = tid + 256 * i;
            if (p < NSENT * 100) {
                int sent = psent[i], m = pm[i];
                const unsigned short* xr = &Xc[buf][sent * 400 + m];
                float gi = bf2f(Gl[sent][m])       + bf2f(xr[0])   + bc_r[i][0];
                float gf = bf2f(Gl[sent][100 + m]) + bf2f(xr[100]) + bc_r[i][1];
                float gg = bf2f(Gl[sent][200 + m]) + bf2f(xr[200]) + bc_r[i][2];
                float go = bf2f(Gl[sent][300 + m]) + bf2f(xr[300]) + bc_r[i][3];
                float c = sigm(gf) * c_reg[i] + sigm(gi) * tanha(gg);
                float h = sigm(go) * tanha(c);
                c_reg[i] = c;
                Hl[sent][m] = f2bf(h);
                if (step == 63) {
                    long b = s0 + sent;
                    if (b < NV_B) hid[b * 200 + dir * 100 + m] = h;
                }
            }
        }
        // land staged inputs into the other buffer
        if (step < 63) {
            *(bf16x8*)&Xc[buf ^ 1][tid * 8] = stg0;
            if (u1 < NSENT * 50) *(bf16x8*)&Xc[buf ^ 1][u1 * 8] = stg1;
        }
        __syncthreads();   // barrier 2
    }
}

// ---------------- similarity / partition glue ----------------
__global__ void k_u(const float* __restrict__ hid, const float* __restrict__ simw, float* __restrict__ u) {
    int j = threadIdx.x;
    if (j < 200) {
        float s = 0.f;
        for (int a = 0; a < 200; a++) s += hid[a] * simw[a * 200 + j];
        u[j] = s;
    }
}

__global__ void k_logits(const float* __restrict__ hid, const float* __restrict__ u,
                         const float* __restrict__ simb, float* __restrict__ logits) {
    int s = blockIdx.x * 256 + threadIdx.x;
    if (s < NV_S) {
        const float* row = hid + (long)(1 + s) * 200;
        float acc = 0.f;
        for (int j = 0; j < 200; j++) acc += row[j] * u[j];
        logits[s] = acc + simb[0];
    }
}

__global__ __launch_bounds__(256) void k_glue(const float* __restrict__ logits, float* __restrict__ prob,
                                              int* __restrict__ dhigh, int* __restrict__ dlow,
                                              int* __restrict__ counts) {
    __shared__ float red[256];
    __shared__ int cnt[256];
    __shared__ float smax, ssum;
    __shared__ int offs[257];
    int tid = threadIdx.x;
    float sg[8];
    int mk[8];
    float lmax = -3e38f;
    int lc = 0;
#pragma unroll
    for (int i = 0; i < 8; i++) {
        int s = tid * 8 + i;
        float x = 1.f / (1.f + __expf(-logits[s]));
        sg[i] = x;
        mk[i] = (x >= 0.5f) ? 1 : 0;
        lc += mk[i];
        lmax = fmaxf(lmax, x);
    }
    red[tid] = lmax;
    cnt[tid] = lc;
    __syncthreads();
    for (int d = 128; d > 0; d >>= 1) {
        if (tid < d) red[tid] = fmaxf(red[tid], red[tid + d]);
        __syncthreads();
    }
    if (tid == 0) smax = red[0];
    __syncthreads();
    float le = 0.f;
#pragma unroll
    for (int i = 0; i < 8; i++) le += __expf(sg[i] - smax);
    red[tid] = le;
    __syncthreads();
    for (int d = 128; d > 0; d >>= 1) {
        if (tid < d) red[tid] += red[tid + d];
        __syncthreads();
    }
    if (tid == 0) {
        ssum = red[0];
        int run = 0;
        for (int i = 0; i < 256; i++) { offs[i] = run; run += cnt[i]; }
        offs[256] = run;
        counts[0] = run;
        counts[1] = NV_S - run;
    }
    __syncthreads();
    int nh = offs[256];
    int tpos = offs[tid];
    int fpos = tid * 8 - tpos;
    float inv = 1.f / ssum;
#pragma unroll
    for (int i = 0; i < 8; i++) {
        int s = tid * 8 + i;
        prob[s] = __expf(sg[i] - smax) * inv;
        if (mk[i]) { dhigh[s] = tpos; dlow[s] = (NV_S - nh) + tpos; tpos++; }
        else { dhigh[s] = nh + fpos; dlow[s] = fpos; fpos++; }
    }
}

__global__ void k_scatter(const float* __restrict__ hid, const float* __restrict__ prob,
                          const int* __restrict__ dhigh, const int* __restrict__ dlow,
                          unsigned short* __restrict__ Xh, unsigned short* __restrict__ Xl) {
    int s = blockIdx.x;
    int j = threadIdx.x;
    if (j < 200) {
        float v = prob[s] * hid[(long)(1 + s) * 200 + j];
        unsigned short b = f2bf(v);
        Xh[(long)dhigh[s] * 200 + j] = b;
        Xl[(long)dlow[s] * 200 + j] = b;
    }
}

// ---------------- column softmax v2: 3-phase split with row-wide 16B loads ----------------
// softmax over s (rows) per column t, of f = indicator ? v/sqrt(200) : (1-v)/sqrt(200)
// Phase A: per-(head, 32-row chunk) online (m,l) partials per column. 512 blocks.
#define CS_NCH 64          // chunks of 32 rows
__global__ __launch_bounds__(256) void k_colsoft_a(const unsigned short* __restrict__ Sb,
                                                   const int* __restrict__ nvp, int indicator,
                                                   float* __restrict__ pmb, float* __restrict__ plb) {
    int tid = threadIdx.x;
    int ch = blockIdx.x, h = blockIdx.y;
    int nv = *nvp;
    int s0 = ch * 32;
    const float inv = 0.0707106781f;  // 1/sqrt(200)
    const unsigned short* Sh = Sb + (long)h * NV_S * NV_S;
    float m[8], l[8];
#pragma unroll
    for (int j = 0; j < 8; j++) { m[j] = -3e38f; l[j] = 0.f; }
#pragma unroll 4
    for (int r = 0; r < 32; r++) {
        int s = s0 + r;
        if (s >= nv) break;
        bf16x8 row = *(const bf16x8*)(Sh + (long)s * NV_S + tid * 8);
#pragma unroll
        for (int j = 0; j < 8; j++) {
            float v = bf2f((unsigned short)row[j]);
            float f = indicator ? v * inv : (1.f - v) * inv;
            if (f > m[j]) { l[j] = l[j] * __expf(m[j] - f) + 1.f; m[j] = f; }
            else l[j] += __expf(f - m[j]);
        }
    }
    long base = ((long)h * CS_NCH + ch) * NV_S + tid * 8;
    float4 m0 = {m[0], m[1], m[2], m[3]}, m1 = {m[4], m[5], m[6], m[7]};
    float4 l0 = {l[0], l[1], l[2], l[3]}, l1 = {l[4], l[5], l[6], l[7]};
    *(float4*)&pmb[base] = m0; *(float4*)&pmb[base + 4] = m1;
    *(float4*)&plb[base] = l0; *(float4*)&plb[base + 4] = l1;
}

// Phase B: merge chunk partials per column -> Mcol, Zcol (= tmask/L). 64 blocks.
__global__ __launch_bounds__(256) void k_colsoft_b(const float* __restrict__ pmb,
                                                   const float* __restrict__ plb,
                                                   const int* __restrict__ nvp,
                                                   float* __restrict__ Mcol, float* __restrict__ Zcol) {
    int c = blockIdx.x * 256 + threadIdx.x;   // c in [0, 8*2048)
    int h = c >> 11, t = c & 2047;
    int nv = *nvp;
    long base = (long)h * CS_NCH * NV_S + t;
    float M = -3e38f;
    for (int ch = 0; ch < CS_NCH; ch++) M = fmaxf(M, pmb[base + (long)ch * NV_S]);
    float L = 0.f;
    for (int ch = 0; ch < CS_NCH; ch++) {
        float mc = pmb[base + (long)ch * NV_S];
        float lc = plb[base + (long)ch * NV_S];
        L += lc * __expf(mc - M);
    }
    Mcol[c] = M;
    Zcol[c] = (t < nv) ? (1.f / L) : 0.f;
}

// Phase C: normalize & write P in place. 1024 blocks, 16 rows each, 16B loads+stores.
__global__ __launch_bounds__(256) void k_colsoft_c(unsigned short* __restrict__ Sb,
                                                   const int* __restrict__ nvp, int indicator,
                                                   const float* __restrict__ Mcol,
                                                   const float* __restrict__ Zcol) {
    int tid = threadIdx.x;
    int ch = blockIdx.x, h = blockIdx.y;
    int nv = *nvp;
    int s0 = ch * 16;
    const float inv = 0.0707106781f;
    unsigned short* Sh = Sb + (long)h * NV_S * NV_S;
    long cb = (long)h * NV_S + tid * 8;
    float4 Ma = *(const float4*)&Mcol[cb], Mb = *(const float4*)&Mcol[cb + 4];
    float4 Za = *(const float4*)&Zcol[cb], Zb = *(const float4*)&Zcol[cb + 4];
    float M[8] = {Ma.x, Ma.y, Ma.z, Ma.w, Mb.x, Mb.y, Mb.z, Mb.w};
    float Z[8] = {Za.x, Za.y, Za.z, Za.w, Zb.x, Zb.y, Zb.z, Zb.w};
#pragma unroll 2
    for (int r = 0; r < 16; r++) {
        int s = s0 + r;
        unsigned short* p = Sh + (long)s * NV_S + tid * 8;
        bf16x8 outv;
        if (s < nv) {
            bf16x8 row = *(const bf16x8*)p;
#pragma unroll
            for (int j = 0; j < 8; j++) {
                float v = bf2f((unsigned short)row[j]);
                float f = indicator ? v * inv : (1.f - v) * inv;
                outv[j] = (short)f2bf(__expf(f - M[j]) * Z[j]);
            }
        } else {
#pragma unroll
            for (int j = 0; j < 8; j++) outv[j] = 0;
        }
        *(bf16x8*)p = outv;
    }
}

// ---------------- final feature matvec ----------------
__global__ void k_initout(const float* __restrict__ featb, float* __restrict__ out) {
    int j = threadIdx.x + blockIdx.x * 256;
    if (j < 400) out[j] = featb[j % 200];
}

__global__ __launch_bounds__(256) void k_feat(const float* __restrict__ mh, const float* __restrict__ featw,
                                              float* __restrict__ out) {
    __shared__ float red0[256], red1[256];
    int j = blockIdx.x, ch = blockIdx.y, tid = threadIdx.x;
    long base = (long)ch * 102400;
    const float4* wrow = (const float4*)(featw + (long)j * 409600 + base);
    const float4* mh_h = (const float4*)(mh + base);
    const float4* mh_l = (const float4*)(mh + 409600 + base);
    float ah = 0.f, al = 0.f;
    for (int r = tid; r < 25600; r += 256) {
        float4 w = wrow[r];
        float4 a = mh_h[r];
        float4 b = mh_l[r];
        ah += w.x * a.x + w.y * a.y + w.z * a.z + w.w * a.w;
        al += w.x * b.x + w.y * b.y + w.z * b.z + w.w * b.w;
    }
    red0[tid] = ah;
    red1[tid] = al;
    __syncthreads();
    for (int d = 128; d > 0; d >>= 1) {
        if (tid < d) { red0[tid] += red0[tid + d]; red1[tid] += red1[tid + d]; }
        __syncthreads();
    }
    if (tid == 0) {
        atomicAdd(&out[j], red0[0]);
        atomicAdd(&out[200 + j], red1[0]);
    }
}

// ---------------- host launch ----------------
extern "C" void kernel_launch(void* const* d_in, const int* in_sizes, int n_in,
                              void* d_out, int out_size, void* d_ws, size_t ws_size,
                              hipStream_t stream) {
    const int* rsent = (const int*)d_in[0];
    const int* body = (const int*)d_in[1];
    const float* emb = (const float*)d_in[2];
    const float* wihf = (const float*)d_in[3];
    const float* whhf = (const float*)d_in[4];
    const float* bihf = (const float*)d_in[5];
    const float* bhhf = (const float*)d_in[6];
    const float* wihb = (const float*)d_in[7];
    const float* whhb = (const float*)d_in[8];
    const float* bihb = (const float*)d_in[9];
    const float* bhhb = (const float*)d_in[10];
    const float* simw = (const float*)d_in[11];
    const float* simb = (const float*)d_in[12];
    const float* qw = (const float*)d_in[13];
    const float* qb = (const float*)d_in[14];
    const float* kw = (const float*)d_in[15];
    const float* kb = (const float*)d_in[16];
    const float* vw = (const float*)d_in[17];
    const float* vb = (const float*)d_in[18];
    const float* cw = (const float*)d_in[19];
    const float* cb = (const float*)d_in[20];
    const float* fw = (const float*)d_in[21];
    const float* fb = (const float*)d_in[22];
    float* out = (float*)d_out;

    char* ws = (char*)d_ws;
    size_t off = 0;
    auto alloc = [&](size_t b) -> void* {
        void* p = ws + off;
        off += (b + 255) & ~(size_t)255;
        return p;
    };
    unsigned short* embbf = (unsigned short*)alloc(50000L * 304 * 2);
    unsigned short* wih = (unsigned short*)alloc(800L * 304 * 2);
    unsigned short* whh = (unsigned short*)alloc(800L * 136 * 2);
    float* biasc = (float*)alloc(800 * 4);
    unsigned short* qkvw = (unsigned short*)alloc(4800L * 200 * 2);
    float* qkvb = (float*)alloc(4800 * 4);
    unsigned short* cwbf = (unsigned short*)alloc(200L * 1600 * 2);
    unsigned short* vpb = (unsigned short*)alloc(50000L * 800 * 2);
    float* hid = (float*)alloc(2049L * 200 * 4);
    float* u = (float*)alloc(200 * 4);
    float* logits = (float*)alloc(2048 * 4);
    float* prob = (float*)alloc(2048 * 4);
    int* cnts = (int*)alloc(64);
    int* dh = (int*)alloc(2048 * 4);
    int* dl = (int*)alloc(2048 * 4);
    unsigned short* Xh = (unsigned short*)alloc(2048L * 200 * 2);
    unsigned short* Xl = (unsigned short*)alloc(2048L * 200 * 2);
    unsigned short* qkvbuf = (unsigned short*)alloc(2048L * 4800 * 2);
    unsigned short* sbuf = (unsigned short*)alloc(8L * 2048 * 2048 * 2);
    unsigned short* catb = (unsigned short*)alloc(2048L * 1600 * 2);
    float* mhbuf = (float*)alloc(2L * 409600 * 4);
    float* pmb = (float*)alloc((long)8 * CS_NCH * 2048 * 4);
    float* plb = (float*)alloc((long)8 * CS_NCH * 2048 * 4);
    float* Mcol = (float*)alloc((long)8 * 2048 * 4);
    float* Zcol = (float*)alloc((long)8 * 2048 * 4);

    prep_emb<<<2048, 256, 0, stream>>>(emb, embbf);
    prep_misc<<<2048, 256, 0, stream>>>(wihf, wihb, whhf, whhb, bihf, bhhf, bihb, bhhb,
                                        qw, qb, kw, kb, vw, vb, cw,
                                        wih, whh, biasc, qkvw, qkvb, cwbf);
    // vocab-wide input projection: [V,300] @ [300,800]
    gemm_bf16<<<dim3(391, 13, 1), 256, 0, stream>>>(
        embbf, 304L, 0L, wih, 304L, 0L, 1,
        vpb, 800L, 0L, 1, nullptr, nullptr, 50000, 800, 300);
    lstm_rec<<<2 * NGRP, 256, 0, stream>>>(vpb, whh, biasc, rsent, body, hid);
    k_u<<<1, 256, 0, stream>>>(hid, simw, u);
    k_logits<<<8, 256, 0, stream>>>(hid, u, simb, logits);
    k_glue<<<1, 256, 0, stream>>>(logits, prob, dh, dl, cnts);
    k_scatter<<<2048, 256, 0, stream>>>(hid, prob, dh, dl, Xh, Xl);

    for (int br = 0; br < 2; br++) {
        const unsigned short* X = (br == 0) ? Xh : Xl;
        const int* nvp = cnts + br;
        int ind = (br == 0) ? 1 : 0;
        // QKV projection: [2048,200] @ [200,4800] + bias
        gemm_bf16<<<dim3(16, 75, 1), 256, 0, stream>>>(
            X, 200L, 0L, qkvw, 200L, 0L, 1,
            qkvbuf, 4800L, 0L, 1, qkvb, nullptr, 2048, 4800, 200);
        // scores: per head Q_h @ K_h^T -> [8][2048][2048]
        gemm_bf16<<<dim3(16, 32, 8), 256, 0, stream>>>(
            qkvbuf, 4800L, 200L, qkvbuf + 1600, 4800L, 200L, 1,
            sbuf, 2048L, (long)2048 * 2048, 1, nullptr, nullptr, 2048, 2048, 200);
        // column softmax (over s), writes P in place — 3-phase split
        k_colsoft_a<<<dim3(CS_NCH, 8), 256, 0, stream>>>(sbuf, nvp, ind, pmb, plb);
        k_colsoft_b<<<64, 256, 0, stream>>>(pmb, plb, nvp, Mcol, Zcol);
        k_colsoft_c<<<dim3(128, 8), 256, 0, stream>>>(sbuf, nvp, ind, Mcol, Zcol);
        // out = P @ V -> cat[s][h*200+o]
        gemm_bf16<<<dim3(16, 4, 8), 256, 0, stream>>>(
            sbuf, 2048L, (long)2048 * 2048, qkvbuf + 3200, 4800L, 200L, 0,
            catb, 1600L, 200L, 1, nullptr, nullptr, 2048, 200, 2048);
        // mh = cat @ concat_w^T + cb, rows >= n_valid zeroed
        gemm_bf16<<<dim3(16, 4, 1), 256, 0, stream>>>(
            catb, 1600L, 0L, cwbf, 1600L, 0L, 1,
            mhbuf + (long)br * 409600, 200L, 0L, 0, cb, nvp, 2048, 200, 1600);
    }
    k_initout<<<2, 256, 0, stream>>>(fb, out);
    k_feat<<<dim3(200, 4, 1), 256, 0, stream>>>(mhbuf, fw, out);
}